// Round 1
// baseline (881.677 us; speedup 1.0000x reference)
//
#include <hip/hip_runtime.h>
#include <math.h>

// ---------------- problem constants ----------------
#define NROWS 48000
#define DIM   256
#define KCB   1024
#define GK    64
#define TM    64      // rows per block in K1

// ---------------- workspace byte offsets ----------------
#define WS_SSUM   0u          // float[1024][256] scatter-add accumulator
#define WS_SCNT   1048576u    // float[1024]
#define WS_GSUM   1052672u    // float[64]
#define WS_GCNT   1052928u    // float[64]
#define WS_CBHI   1053184u    // _Float16[1024*256]
#define WS_CBLO   1577472u    // _Float16[1024*256]
#define WS_ZERO_BYTES 1053184u

// ---------------- output element offsets ----------------
#define OUT_SHAPE 12288000
#define OUT_GAIN  12550144
#define OUT_SNUM  12550208
#define OUT_GNUM  12551232

typedef _Float16 half8  __attribute__((ext_vector_type(8)));
typedef _Float16 half4v __attribute__((ext_vector_type(4)));
typedef float    f32x4  __attribute__((ext_vector_type(4)));

// ---------------- K1 LDS layout (bytes) ----------------
// B double-buffer region overlaps the A staging region (A is consumed into
// registers before B streaming begins).
#define L_BH0 0
#define L_BL0 16640
#define L_BH1 33280
#define L_BL1 49920        // B region ends at 66560
#define L_AHI 0            // 64 rows * 264 halfs * 2B = 33792
#define L_ALO 33792        // ends 67584
#define L_G   67584        // float[64] gain_cb copy
#define L_IND 67840        // int[64]   selected shape index per row
#define L_GQ  68096        // float[64] exp(selected gain) per row
#define L_TOT 68352
// A row stride: 264 halfs (528 B). B pair stride: 1040 B (2 rows of 512 B + 16 B pad)

// K0: split fp32 codebook into f16 hi/lo planes
__global__ __launch_bounds__(256) void k_convert_cb(const float* __restrict__ cb,
                                                    _Float16* __restrict__ hi,
                                                    _Float16* __restrict__ lo) {
    int i = blockIdx.x * 256 + threadIdx.x;   // grid 1024 -> 262144 exact
    float v = cb[i];
    _Float16 h = (_Float16)v;
    hi[i] = h;
    lo[i] = (_Float16)(v - (float)h);
}

__global__ __launch_bounds__(256, 2) void k_main(
    const float* __restrict__ x, const float* __restrict__ cb,
    const float* __restrict__ gcb,
    const _Float16* __restrict__ cbh, const _Float16* __restrict__ cbl,
    float* __restrict__ ws_ssum, float* __restrict__ ws_scnt,
    float* __restrict__ ws_gsum, float* __restrict__ ws_gcnt,
    float* __restrict__ out_q) {
    __shared__ __align__(16) char smem[L_TOT];
    const int tid = threadIdx.x;
    const int bx  = blockIdx.x;
    const long row0 = (long)bx * TM;
    const float* xblk = x + row0 * DIM;

    _Float16* aH = (_Float16*)(smem + L_AHI);
    _Float16* aL = (_Float16*)(smem + L_ALO);
    float* gl    = (float*)(smem + L_G);
    int*   shInd = (int*)(smem + L_IND);
    float* shGq  = (float*)(smem + L_GQ);

    // ---- stage A tile: fp32 -> f16 hi/lo planes in LDS ----
    {
        const float4* xv = (const float4*)xblk;
#pragma unroll
        for (int it = 0; it < 16; ++it) {
            int idx = it * 256 + tid;       // float4 index, 4096 total
            int r = idx >> 6, c4 = idx & 63;
            float4 v = xv[idx];
            _Float16 h0 = (_Float16)v.x, h1 = (_Float16)v.y,
                     h2 = (_Float16)v.z, h3 = (_Float16)v.w;
            half4v hv = {h0, h1, h2, h3};
            half4v lv = {(_Float16)(v.x - (float)h0), (_Float16)(v.y - (float)h1),
                         (_Float16)(v.z - (float)h2), (_Float16)(v.w - (float)h3)};
            *(half4v*)(aH + r * 264 + c4 * 4) = hv;
            *(half4v*)(aL + r * 264 + c4 * 4) = lv;
        }
        if (tid < GK) gl[tid] = gcb[tid];
    }
    __syncthreads();

    // ---- cache A fragments in registers (wave w owns rows w*16..w*16+15) ----
    const int w = tid >> 6, lane = tid & 63;
    const int lc = lane & 15, lq = lane >> 4;
    half8 afh[8], afl[8];
    {
        int rbase = (w * 16 + lc) * 264;
#pragma unroll
        for (int kk = 0; kk < 8; ++kk) {
            int off = rbase + kk * 32 + lq * 8;
            afh[kk] = *(const half8*)(aH + off);
            afl[kk] = *(const half8*)(aL + off);
        }
    }
    __syncthreads();   // A region now reusable for B streaming

    // ---- B chunk DMA: 32 codes (16 row-pairs) per plane, pair stride 1040 B ----
    auto issueChunk = [&](int ch, int buf) {
        const _Float16* srcH = cbh + ch * 32 * DIM;
        const _Float16* srcL = cbl + ch * 32 * DIM;
        char* dH = smem + (buf ? L_BH1 : L_BH0);
        char* dL = smem + (buf ? L_BL1 : L_BL0);
#pragma unroll
        for (int i = 0; i < 4; ++i) {
            int p = w * 4 + i;   // wave-uniform pair index
            __builtin_amdgcn_global_load_lds(
                (const __attribute__((address_space(1))) void*)(srcH + p * 512 + lane * 8),
                (__attribute__((address_space(3))) void*)(dH + p * 1040), 16, 0, 0);
            __builtin_amdgcn_global_load_lds(
                (const __attribute__((address_space(1))) void*)(srcL + p * 512 + lane * 8),
                (__attribute__((address_space(3))) void*)(dL + p * 1040), 16, 0, 0);
        }
    };

    float vmax[4] = {-1e30f, -1e30f, -1e30f, -1e30f};
    int   vidx[4] = {0, 0, 0, 0};

    issueChunk(0, 0);
    __syncthreads();   // barrier drains the DMA (vmcnt(0) before s_barrier)

    for (int ch = 0; ch < 32; ++ch) {
        int buf = ch & 1;
        if (ch + 1 < 32) issueChunk(ch + 1, buf ^ 1);
        const _Float16* bH = (const _Float16*)(smem + (buf ? L_BH1 : L_BH0));
        const _Float16* bL = (const _Float16*)(smem + (buf ? L_BL1 : L_BL0));
#pragma unroll
        for (int sub = 0; sub < 2; ++sub) {
            int lcode = sub * 16 + lc;
            int boff = (lcode >> 1) * 520 + (lcode & 1) * 256;  // halfs
            f32x4 a0 = {0,0,0,0}, a1 = {0,0,0,0}, a2 = {0,0,0,0}, a3 = {0,0,0,0};
#pragma unroll
            for (int kk = 0; kk < 8; ++kk) {
                int o = boff + kk * 32 + lq * 8;
                half8 bh = *(const half8*)(bH + o);
                half8 bl = *(const half8*)(bL + o);
                a0 = __builtin_amdgcn_mfma_f32_16x16x32_f16(afh[kk], bh, a0, 0, 0, 0);
                a1 = __builtin_amdgcn_mfma_f32_16x16x32_f16(afh[kk], bl, a1, 0, 0, 0);
                a2 = __builtin_amdgcn_mfma_f32_16x16x32_f16(afl[kk], bh, a2, 0, 0, 0);
                a3 = __builtin_amdgcn_mfma_f32_16x16x32_f16(afl[kk], bl, a3, 0, 0, 0);
            }
            int code = ch * 32 + sub * 16 + lc;
#pragma unroll
            for (int r = 0; r < 4; ++r) {
                float dv = a0[r] + a1[r] + a2[r] + a3[r];
                if (dv > vmax[r]) { vmax[r] = dv; vidx[r] = code; }
            }
        }
        __syncthreads();
    }

    // ---- argmax reduce across the 16-lane col dimension ----
#pragma unroll
    for (int m = 1; m < 16; m <<= 1) {
#pragma unroll
        for (int r = 0; r < 4; ++r) {
            float ov = __shfl_xor(vmax[r], m, 64);
            int   oi = __shfl_xor(vidx[r], m, 64);
            if (ov > vmax[r] || (ov == vmax[r] && oi < vidx[r])) { vmax[r] = ov; vidx[r] = oi; }
        }
    }
    if (lc == 0) {
#pragma unroll
        for (int r = 0; r < 4; ++r) {
            int lrow = w * 16 + lq * 4 + r;
            float gv = vmax[r];
            int sidx = vidx[r];
            float lg = logf(fmaxf(gv, 1e-5f));
            float bd = 3.4e38f; int gi = 0;
            for (int j = 0; j < GK; ++j) {
                float d = lg - gl[j]; d *= d;
                if (d < bd) { bd = d; gi = j; }
            }
            shInd[lrow] = sidx;
            shGq[lrow]  = expf(gl[gi]);
            atomicAdd(ws_scnt + sidx, 1.0f);
            atomicAdd(ws_gsum + gi, lg);
            atomicAdd(ws_gcnt + gi, 1.0f);
        }
    }
    __syncthreads();

    // ---- epilogue: quantize write + scatter-add of x into shape_sums ----
    {
        const float4* xv = (const float4*)xblk;
        float4* qv = (float4*)(out_q + row0 * DIM);
#pragma unroll
        for (int it = 0; it < 16; ++it) {
            int idx = it * 256 + tid;
            int r = idx >> 6, c4 = idx & 63;
            int code = shInd[r];
            float gq = shGq[r];
            float4 xr = xv[idx];
            const float4 cbv = *(const float4*)(cb + code * DIM + c4 * 4);
            float4 o;
            o.x = gq * cbv.x; o.y = gq * cbv.y; o.z = gq * cbv.z; o.w = gq * cbv.w;
            qv[idx] = o;
            float* ss = ws_ssum + code * DIM + c4 * 4;
            atomicAdd(ss + 0, xr.x); atomicAdd(ss + 1, xr.y);
            atomicAdd(ss + 2, xr.z); atomicAdd(ss + 3, xr.w);
        }
    }
}

// K2: finalize EMA updates / normalizations
__global__ __launch_bounds__(256) void k_final(
    const float* __restrict__ cb, const float* __restrict__ gcb,
    const float* __restrict__ snum, const float* __restrict__ gnum,
    const float* __restrict__ ws_ssum, const float* __restrict__ ws_scnt,
    const float* __restrict__ ws_gsum, const float* __restrict__ ws_gcnt,
    float* __restrict__ out) {
    float* out_shape = out + OUT_SHAPE;
    float* out_gain  = out + OUT_GAIN;
    float* out_snum  = out + OUT_SNUM;
    float* out_gnum  = out + OUT_GNUM;
    int b = blockIdx.x, t = threadIdx.x;
    __shared__ float red[4];
    if (b < KCB) {
        float s = ws_ssum[b * DIM + t];
        float v = s * s;
#pragma unroll
        for (int m = 32; m; m >>= 1) v += __shfl_xor(v, m, 64);
        if ((t & 63) == 0) red[t >> 6] = v;
        __syncthreads();
        float tot = red[0] + red[1] + red[2] + red[3];
        float sn = s / fmaxf(sqrtf(tot), 1e-5f);
        float u = cb[b * DIM + t] * 0.99f + sn * 0.01f;
        __syncthreads();
        v = u * u;
#pragma unroll
        for (int m = 32; m; m >>= 1) v += __shfl_xor(v, m, 64);
        if ((t & 63) == 0) red[t >> 6] = v;
        __syncthreads();
        tot = red[0] + red[1] + red[2] + red[3];
        out_shape[b * DIM + t] = u / fmaxf(sqrtf(tot), 1e-12f);
        if (t == 0) out_snum[b] = snum[b] * 0.99f + ws_scnt[b] * 0.01f;
    } else {
        if (t < GK) {
            float cnt = ws_gcnt[t];
            float gn  = ws_gsum[t] / fmaxf(cnt, 1e-5f);
            out_gain[t] = gcb[t] * 0.99f + gn * 0.01f;
            out_gnum[t] = gnum[t] * 0.99f + cnt * 0.01f;
        }
    }
}

extern "C" void kernel_launch(void* const* d_in, const int* in_sizes, int n_in,
                              void* d_out, int out_size, void* d_ws, size_t ws_size,
                              hipStream_t stream) {
    const float* x    = (const float*)d_in[0];
    const float* cb   = (const float*)d_in[1];
    const float* gcb  = (const float*)d_in[2];
    const float* snum = (const float*)d_in[3];
    const float* gnum = (const float*)d_in[4];
    float* out = (float*)d_out;
    char*  ws  = (char*)d_ws;
    float* ws_ssum = (float*)(ws + WS_SSUM);
    float* ws_scnt = (float*)(ws + WS_SCNT);
    float* ws_gsum = (float*)(ws + WS_GSUM);
    float* ws_gcnt = (float*)(ws + WS_GCNT);
    _Float16* cbh = (_Float16*)(ws + WS_CBHI);
    _Float16* cbl = (_Float16*)(ws + WS_CBLO);

    hipMemsetAsync(d_ws, 0, WS_ZERO_BYTES, stream);
    k_convert_cb<<<1024, 256, 0, stream>>>(cb, cbh, cbl);
    k_main<<<NROWS / TM, 256, 0, stream>>>(x, cb, gcb, cbh, cbl,
                                           ws_ssum, ws_scnt, ws_gsum, ws_gcnt, out);
    k_final<<<KCB + 1, 256, 0, stream>>>(cb, gcb, snum, gnum,
                                         ws_ssum, ws_scnt, ws_gsum, ws_gcnt, out);
}

// Round 2
// 810.090 us; speedup vs baseline: 1.0884x; 1.0884x over previous
//
#include <hip/hip_runtime.h>
#include <math.h>

// ---------------- problem constants ----------------
#define NROWS 48000
#define DIM   256
#define KCB   1024
#define GK    64
#define TM    128     // rows per block in K1

// ---------------- workspace byte offsets ----------------
#define WS_SCNT    0u         // int[1024]
#define WS_GSUM    4096u      // float[64]
#define WS_GCNT    4352u      // float[64]
#define WS_OFFS    4608u      // int[1024]
#define WS_CURS    8704u      // int[1024]
#define WS_ROWCODE 12800u     // int[48000]
#define WS_BUCKET  204800u    // int[48000]
#define WS_CBHI    396800u    // _Float16[1024*256] swizzled
#define WS_CBLO    921088u    // _Float16[1024*256] swizzled
#define WS_ZERO_BYTES 4608u

// ---------------- output element offsets ----------------
#define OUT_SHAPE 12288000
#define OUT_GAIN  12550144
#define OUT_SNUM  12550208
#define OUT_GNUM  12551232

typedef _Float16 half8  __attribute__((ext_vector_type(8)));
typedef _Float16 half4v __attribute__((ext_vector_type(4)));
typedef float    f32x4  __attribute__((ext_vector_type(4)));

// ---------------- K1 LDS layout (bytes) ----------------
// B double-buffer (2 bufs x 2 planes x 16 KB = 64 KB) overlaps the A staging
// region (A consumed into registers before B streaming begins).
#define L_B0H 0
#define L_B0L 16384
#define L_B1H 32768
#define L_B1L 49152        // B ends 65536
#define L_AHI 0            // 64 rows * 264 halfs * 2 B = 33792
#define L_ALO 33792        // ends 67584
#define L_G   67584        // float[64]
#define L_IND 67840        // int[128]
#define L_GQ  68352        // float[128]
#define L_TOT 68864

// K0: split fp32 codebook into f16 hi/lo planes, PRE-SWIZZLED into MFMA
// fragment order so the chunk DMA is linear and ds_read_b128 is conflict-free.
// Chunk ch = 32 codes. Within a chunk-plane (8192 halfs):
//   idx = (sub*8+kk)*512 + lc*32 + lq*8 + e
// where code = ch*32 + sub*16 + lc, k = kk*32 + lq*8 + e.
__global__ __launch_bounds__(256) void k_convert_cb(const float* __restrict__ cb,
                                                    _Float16* __restrict__ hi,
                                                    _Float16* __restrict__ lo) {
    int i = blockIdx.x * 256 + threadIdx.x;   // 262144 total
    float v = cb[i];
    int code = i >> 8, k = i & 255;
    int ch = code >> 5, c32 = code & 31;
    int sub = c32 >> 4, lc = c32 & 15;
    int kk = k >> 5, lq = (k & 31) >> 3, e = k & 7;
    int dst = ch * 8192 + (sub * 8 + kk) * 512 + lc * 32 + lq * 8 + e;
    _Float16 h = (_Float16)v;
    hi[dst] = h;
    lo[dst] = (_Float16)(v - (float)h);
}

__global__ __launch_bounds__(256, 2) void k_main(
    const float* __restrict__ x, const float* __restrict__ cb,
    const float* __restrict__ gcb,
    const _Float16* __restrict__ cbh, const _Float16* __restrict__ cbl,
    int* __restrict__ ws_scnt, float* __restrict__ ws_gsum,
    float* __restrict__ ws_gcnt, int* __restrict__ ws_rowcode,
    float* __restrict__ out_q) {
    __shared__ __align__(16) char smem[L_TOT];
    const int tid = threadIdx.x;
    const int w = tid >> 6, lane = tid & 63;
    const int lc = lane & 15, lq = lane >> 4;
    const int row0 = blockIdx.x * TM;

    _Float16* aH = (_Float16*)(smem + L_AHI);
    _Float16* aL = (_Float16*)(smem + L_ALO);
    float* gl    = (float*)(smem + L_G);
    int*   shInd = (int*)(smem + L_IND);
    float* shGq  = (float*)(smem + L_GQ);

    if (tid < GK) gl[tid] = gcb[tid];

    // ---- stage A in two 64-row phases; cache fragments in registers ----
    half8 afh[2][8], afl[2][8];
#pragma unroll
    for (int ph = 0; ph < 2; ++ph) {
        __syncthreads();
        const float4* xv = (const float4*)(x + (row0 + ph * 64) * DIM);
#pragma unroll
        for (int it = 0; it < 16; ++it) {
            int idx = it * 256 + tid;       // 4096 float4s
            int r = idx >> 6, c4 = idx & 63;
            float4 v = xv[idx];
            _Float16 h0 = (_Float16)v.x, h1 = (_Float16)v.y,
                     h2 = (_Float16)v.z, h3 = (_Float16)v.w;
            half4v hv = {h0, h1, h2, h3};
            half4v lv = {(_Float16)(v.x - (float)h0), (_Float16)(v.y - (float)h1),
                         (_Float16)(v.z - (float)h2), (_Float16)(v.w - (float)h3)};
            *(half4v*)(aH + r * 264 + c4 * 4) = hv;
            *(half4v*)(aL + r * 264 + c4 * 4) = lv;
        }
        __syncthreads();
        if ((w >> 1) == ph) {
            int wl = w & 1;
#pragma unroll
            for (int s = 0; s < 2; ++s) {
                int rb = (wl * 32 + s * 16 + lc) * 264;
#pragma unroll
                for (int kk = 0; kk < 8; ++kk) {
                    int off = rb + kk * 32 + lq * 8;
                    afh[s][kk] = *(const half8*)(aH + off);
                    afl[s][kk] = *(const half8*)(aL + off);
                }
            }
        }
    }
    __syncthreads();   // frag reads done; A region now reusable for B

    // ---- B chunk DMA: linear (swizzled layout), 4 KB/plane per wave ----
    auto issueChunk = [&](int ch, int buf) {
        const char* srcH = (const char*)cbh + ch * 16384;
        const char* srcL = (const char*)cbl + ch * 16384;
        char* dH = smem + (buf ? L_B1H : L_B0H);
        char* dL = smem + (buf ? L_B1L : L_B0L);
#pragma unroll
        for (int i = 0; i < 4; ++i) {
            int off = w * 4096 + i * 1024;   // wave-uniform LDS base
            __builtin_amdgcn_global_load_lds(
                (const __attribute__((address_space(1))) void*)(srcH + off + lane * 16),
                (__attribute__((address_space(3))) void*)(dH + off), 16, 0, 0);
            __builtin_amdgcn_global_load_lds(
                (const __attribute__((address_space(1))) void*)(srcL + off + lane * 16),
                (__attribute__((address_space(3))) void*)(dL + off), 16, 0, 0);
        }
    };

    float vmax[2][4];
    int   vidx[2][4];
#pragma unroll
    for (int s = 0; s < 2; ++s)
#pragma unroll
        for (int r = 0; r < 4; ++r) { vmax[s][r] = -1e30f; vidx[s][r] = 0; }

    issueChunk(0, 0);
    __syncthreads();

    for (int ch = 0; ch < 32; ++ch) {
        int buf = ch & 1;
        if (ch + 1 < 32) issueChunk(ch + 1, buf ^ 1);
        const _Float16* bH = (const _Float16*)(smem + (buf ? L_B1H : L_B0H));
        const _Float16* bL = (const _Float16*)(smem + (buf ? L_B1L : L_B0L));
#pragma unroll
        for (int sub = 0; sub < 2; ++sub) {
            f32x4 acc[2][4];
#pragma unroll
            for (int s = 0; s < 2; ++s)
#pragma unroll
                for (int c = 0; c < 4; ++c) acc[s][c] = (f32x4){0, 0, 0, 0};
#pragma unroll
            for (int kk = 0; kk < 8; ++kk) {
                int o = (sub * 8 + kk) * 512 + (lc * 4 + lq) * 8;  // halfs
                half8 bh = *(const half8*)(bH + o);
                half8 bl = *(const half8*)(bL + o);
#pragma unroll
                for (int s = 0; s < 2; ++s) {
                    acc[s][0] = __builtin_amdgcn_mfma_f32_16x16x32_f16(afh[s][kk], bh, acc[s][0], 0, 0, 0);
                    acc[s][1] = __builtin_amdgcn_mfma_f32_16x16x32_f16(afh[s][kk], bl, acc[s][1], 0, 0, 0);
                    acc[s][2] = __builtin_amdgcn_mfma_f32_16x16x32_f16(afl[s][kk], bh, acc[s][2], 0, 0, 0);
                    acc[s][3] = __builtin_amdgcn_mfma_f32_16x16x32_f16(afl[s][kk], bl, acc[s][3], 0, 0, 0);
                }
            }
            int code = ch * 32 + sub * 16 + lc;
#pragma unroll
            for (int s = 0; s < 2; ++s)
#pragma unroll
                for (int r = 0; r < 4; ++r) {
                    float dv = acc[s][0][r] + acc[s][1][r] + acc[s][2][r] + acc[s][3][r];
                    if (dv > vmax[s][r]) { vmax[s][r] = dv; vidx[s][r] = code; }
                }
        }
        __syncthreads();
    }

    // ---- argmax reduce across the 16-lane col (lc) dimension ----
#pragma unroll
    for (int m = 1; m < 16; m <<= 1) {
#pragma unroll
        for (int s = 0; s < 2; ++s)
#pragma unroll
            for (int r = 0; r < 4; ++r) {
                float ov = __shfl_xor(vmax[s][r], m, 64);
                int   oi = __shfl_xor(vidx[s][r], m, 64);
                if (ov > vmax[s][r] || (ov == vmax[s][r] && oi < vidx[s][r])) {
                    vmax[s][r] = ov; vidx[s][r] = oi;
                }
            }
    }
    if (lc == 0) {
#pragma unroll
        for (int s = 0; s < 2; ++s)
#pragma unroll
            for (int r = 0; r < 4; ++r) {
                int lrow = w * 32 + s * 16 + lq * 4 + r;
                float gv = vmax[s][r];
                int sidx = vidx[s][r];
                float lg = logf(fmaxf(gv, 1e-5f));
                float bd = 3.4e38f; int gi = 0;
                for (int j = 0; j < GK; ++j) {
                    float d = lg - gl[j]; d *= d;
                    if (d < bd) { bd = d; gi = j; }
                }
                shInd[lrow] = sidx;
                shGq[lrow]  = expf(gl[gi]);
                ws_rowcode[row0 + lrow] = sidx;
                atomicAdd(ws_scnt + sidx, 1);
                atomicAdd(ws_gsum + gi, lg);
                atomicAdd(ws_gcnt + gi, 1.0f);
            }
    }
    __syncthreads();

    // ---- epilogue: quantize = exp(gain_q) * cb[code] (no x re-read) ----
    {
        float4* qv = (float4*)(out_q + (long)row0 * DIM);
#pragma unroll
        for (int it = 0; it < 32; ++it) {
            int idx = it * 256 + tid;       // 8192 float4s
            int r = idx >> 6, c4 = idx & 63;
            int code = shInd[r];
            float gq = shGq[r];
            const float4 cbv = *(const float4*)(cb + code * DIM + c4 * 4);
            float4 o;
            o.x = gq * cbv.x; o.y = gq * cbv.y; o.z = gq * cbv.z; o.w = gq * cbv.w;
            qv[idx] = o;
        }
    }
}

// K2a: exclusive prefix scan of code counts -> bucket offsets + cursors
__global__ __launch_bounds__(1024) void k_scan(const int* __restrict__ scnt,
                                               int* __restrict__ offs,
                                               int* __restrict__ curs) {
    int t = threadIdx.x;
    __shared__ int sc[1024];
    int my = scnt[t];
    sc[t] = my;
    __syncthreads();
    for (int d = 1; d < 1024; d <<= 1) {
        int v = (t >= d) ? sc[t - d] : 0;
        __syncthreads();
        sc[t] += v;
        __syncthreads();
    }
    int ex = sc[t] - my;
    offs[t] = ex;
    curs[t] = ex;
}

// K2b: scatter row ids into code-sorted buckets
__global__ __launch_bounds__(256) void k_scatter(const int* __restrict__ rowcode,
                                                 int* __restrict__ curs,
                                                 int* __restrict__ bucket) {
    int i = blockIdx.x * 256 + threadIdx.x;
    if (i < NROWS) {
        int code = rowcode[i];
        int pos = atomicAdd(curs + code, 1);
        bucket[pos] = i;
    }
}

// K2c: per-code column reduction of x + full shape/gain finalize
__global__ __launch_bounds__(256) void k_reduce(
    const float* __restrict__ x, const float* __restrict__ cb,
    const float* __restrict__ gcb, const float* __restrict__ snum,
    const float* __restrict__ gnum,
    const int* __restrict__ scnt, const int* __restrict__ offs,
    const int* __restrict__ bucket,
    const float* __restrict__ gsum, const float* __restrict__ gcnt,
    float* __restrict__ out) {
    int b = blockIdx.x, t = threadIdx.x;
    if (b < KCB) {
        int cnt = scnt[b], base = offs[b];
        float s = 0.0f;
        int i = 0;
        for (; i + 4 <= cnt; i += 4) {
            int r0 = bucket[base + i], r1 = bucket[base + i + 1];
            int r2 = bucket[base + i + 2], r3 = bucket[base + i + 3];
            float v0 = x[r0 * DIM + t], v1 = x[r1 * DIM + t];
            float v2 = x[r2 * DIM + t], v3 = x[r3 * DIM + t];
            s += v0 + v1 + v2 + v3;
        }
        for (; i < cnt; ++i) {
            int r = bucket[base + i];
            s += x[r * DIM + t];
        }
        __shared__ float red[4];
        int w = t >> 6;
        float v = s * s;
#pragma unroll
        for (int m = 32; m; m >>= 1) v += __shfl_xor(v, m, 64);
        if ((t & 63) == 0) red[w] = v;
        __syncthreads();
        float tot = red[0] + red[1] + red[2] + red[3];
        float sn = s / fmaxf(sqrtf(tot), 1e-5f);
        float u = cb[b * DIM + t] * 0.99f + 0.01f * sn;
        __syncthreads();
        v = u * u;
#pragma unroll
        for (int m = 32; m; m >>= 1) v += __shfl_xor(v, m, 64);
        if ((t & 63) == 0) red[w] = v;
        __syncthreads();
        tot = red[0] + red[1] + red[2] + red[3];
        out[OUT_SHAPE + b * DIM + t] = u / fmaxf(sqrtf(tot), 1e-12f);
        if (t == 0) out[OUT_SNUM + b] = snum[b] * 0.99f + 0.01f * (float)cnt;
    } else if (t < GK) {
        float cnt = gcnt[t];
        float gn  = gsum[t] / fmaxf(cnt, 1e-5f);
        out[OUT_GAIN + t] = gcb[t] * 0.99f + 0.01f * gn;
        out[OUT_GNUM + t] = gnum[t] * 0.99f + 0.01f * cnt;
    }
}

extern "C" void kernel_launch(void* const* d_in, const int* in_sizes, int n_in,
                              void* d_out, int out_size, void* d_ws, size_t ws_size,
                              hipStream_t stream) {
    const float* x    = (const float*)d_in[0];
    const float* cb   = (const float*)d_in[1];
    const float* gcb  = (const float*)d_in[2];
    const float* snum = (const float*)d_in[3];
    const float* gnum = (const float*)d_in[4];
    float* out = (float*)d_out;
    char*  ws  = (char*)d_ws;
    int*   ws_scnt    = (int*)(ws + WS_SCNT);
    float* ws_gsum    = (float*)(ws + WS_GSUM);
    float* ws_gcnt    = (float*)(ws + WS_GCNT);
    int*   ws_offs    = (int*)(ws + WS_OFFS);
    int*   ws_curs    = (int*)(ws + WS_CURS);
    int*   ws_rowcode = (int*)(ws + WS_ROWCODE);
    int*   ws_bucket  = (int*)(ws + WS_BUCKET);
    _Float16* cbh = (_Float16*)(ws + WS_CBHI);
    _Float16* cbl = (_Float16*)(ws + WS_CBLO);

    hipMemsetAsync(d_ws, 0, WS_ZERO_BYTES, stream);
    k_convert_cb<<<1024, 256, 0, stream>>>(cb, cbh, cbl);
    k_main<<<NROWS / TM, 256, 0, stream>>>(x, cb, gcb, cbh, cbl,
                                           ws_scnt, ws_gsum, ws_gcnt, ws_rowcode, out);
    k_scan<<<1, 1024, 0, stream>>>(ws_scnt, ws_offs, ws_curs);
    k_scatter<<<(NROWS + 255) / 256, 256, 0, stream>>>(ws_rowcode, ws_curs, ws_bucket);
    k_reduce<<<KCB + 1, 256, 0, stream>>>(x, cb, gcb, snum, gnum,
                                          ws_scnt, ws_offs, ws_bucket,
                                          ws_gsum, ws_gcnt, out);
}

// Round 3
// 793.347 us; speedup vs baseline: 1.1113x; 1.0211x over previous
//
#include <hip/hip_runtime.h>
#include <math.h>

// ---------------- problem constants ----------------
#define NROWS 48000
#define DIM   256
#define KCB   1024
#define GK    64
#define TM    64      // rows per block in K1
#define NCH   64      // chunks of 16 codes

// ---------------- workspace byte offsets ----------------
#define WS_SCNT    0u         // int[1024]
#define WS_GSUM    4096u      // float[64]
#define WS_GCNT    4352u      // float[64]
#define WS_OFFS    4608u      // int[1024]
#define WS_CURS    8704u      // int[1024]
#define WS_ROWCODE 12800u     // int[48000]
#define WS_BUCKET  204800u    // int[48000]
#define WS_CBHI    396800u    // _Float16[1024*256] swizzled (512 KB)
#define WS_CBLO    921088u    // _Float16[1024*256] swizzled (512 KB)
#define WS_ZERO_BYTES 4608u

// ---------------- output element offsets ----------------
#define OUT_SHAPE 12288000
#define OUT_GAIN  12550144
#define OUT_SNUM  12550208
#define OUT_GNUM  12551232

typedef _Float16 half8  __attribute__((ext_vector_type(8)));
typedef _Float16 half4v __attribute__((ext_vector_type(4)));
typedef float    f32x4  __attribute__((ext_vector_type(4)));

// ---------------- K1 LDS layout (bytes) ----------------
// B double-buffer: 2 bufs x (hi 8 KB + lo 8 KB) = 32 KB, aliased with the
// 32-row A staging region (A consumed into registers before B streaming).
#define L_B    0           // buf b at b*16384: hi at +0, lo at +8192
#define L_AHI  0           // 32 rows * 264 halfs * 2 B = 16896
#define L_ALO  16896       // ends 33792
#define L_G    33792       // float[64]
#define L_IND  34048       // int[64]
#define L_GQ   34304       // float[64]
#define L_LG   34560       // float[64] raw max-dot per row
#define L_TOT  34816

// K0: split fp32 codebook into f16 hi/lo planes, pre-swizzled into MFMA
// fragment order for 16-code chunks so chunk DMA is linear and ds_read_b128
// is conflict-free. dst(halfs) = ch*4096 + kk*512 + lc*32 + lq*8 + e
// where code = ch*16+lc, k = kk*32 + lq*8 + e.
__global__ __launch_bounds__(256) void k_convert_cb(const float* __restrict__ cb,
                                                    _Float16* __restrict__ hi,
                                                    _Float16* __restrict__ lo) {
    int i = blockIdx.x * 256 + threadIdx.x;   // 262144 total
    float v = cb[i];
    int code = i >> 8, k = i & 255;
    int ch = code >> 4, lc = code & 15;
    int kk = k >> 5, lq = (k & 31) >> 3, e = k & 7;
    int dst = ch * 4096 + kk * 512 + lc * 32 + lq * 8 + e;
    _Float16 h = (_Float16)v;
    hi[dst] = h;
    lo[dst] = (_Float16)(v - (float)h);
}

__global__ __launch_bounds__(256, 3) void k_main(
    const float* __restrict__ x, const float* __restrict__ cb,
    const float* __restrict__ gcb,
    const _Float16* __restrict__ cbh, const _Float16* __restrict__ cbl,
    int* __restrict__ ws_scnt, float* __restrict__ ws_gsum,
    float* __restrict__ ws_gcnt, int* __restrict__ ws_rowcode,
    float* __restrict__ out_q) {
    __shared__ __align__(16) char smem[L_TOT];
    const int tid = threadIdx.x;
    const int w = tid >> 6, lane = tid & 63;
    const int lc = lane & 15, lq = lane >> 4;
    const int row0 = blockIdx.x * TM;

    _Float16* aH = (_Float16*)(smem + L_AHI);
    _Float16* aL = (_Float16*)(smem + L_ALO);
    float* gl    = (float*)(smem + L_G);
    int*   shInd = (int*)(smem + L_IND);
    float* shGq  = (float*)(smem + L_GQ);
    float* shLg  = (float*)(smem + L_LG);

    if (tid < GK) gl[tid] = gcb[tid];

    // ---- stage A in two 32-row phases; cache one 16-row frag set / wave ----
    half8 afh[8], afl[8];
#pragma unroll
    for (int ph = 0; ph < 2; ++ph) {
        __syncthreads();
        const float4* xv = (const float4*)(x + (row0 + ph * 32) * DIM);
#pragma unroll
        for (int it = 0; it < 8; ++it) {
            int idx = it * 256 + tid;       // 2048 float4s
            int r = idx >> 6, c4 = idx & 63;
            float4 v = xv[idx];
            _Float16 h0 = (_Float16)v.x, h1 = (_Float16)v.y,
                     h2 = (_Float16)v.z, h3 = (_Float16)v.w;
            half4v hv = {h0, h1, h2, h3};
            half4v lv = {(_Float16)(v.x - (float)h0), (_Float16)(v.y - (float)h1),
                         (_Float16)(v.z - (float)h2), (_Float16)(v.w - (float)h3)};
            *(half4v*)(aH + r * 264 + c4 * 4) = hv;
            *(half4v*)(aL + r * 264 + c4 * 4) = lv;
        }
        __syncthreads();
        if ((w >> 1) == ph) {
            int wl = w & 1;
            int rb = (wl * 16 + lc) * 264;
#pragma unroll
            for (int kk = 0; kk < 8; ++kk) {
                int off = rb + kk * 32 + lq * 8;
                afh[kk] = *(const half8*)(aH + off);
                afl[kk] = *(const half8*)(aL + off);
            }
        }
    }
    __syncthreads();   // frag reads done; A region now reusable for B

    // ---- B chunk DMA: 16 codes = hi 8 KB + lo 8 KB, linear, 4 insts/wave ----
    auto issueChunk = [&](int ch, int buf) {
        const char* srcH = (const char*)cbh + ch * 8192;
        const char* srcL = (const char*)cbl + ch * 8192;
        char* d = smem + buf * 16384;
#pragma unroll
        for (int i = 0; i < 2; ++i) {
            int off = w * 2048 + i * 1024;   // wave-uniform LDS base
            __builtin_amdgcn_global_load_lds(
                (const __attribute__((address_space(1))) void*)(srcH + off + lane * 16),
                (__attribute__((address_space(3))) void*)(d + off), 16, 0, 0);
            __builtin_amdgcn_global_load_lds(
                (const __attribute__((address_space(1))) void*)(srcL + off + lane * 16),
                (__attribute__((address_space(3))) void*)(d + 8192 + off), 16, 0, 0);
        }
    };

    float vmax[4] = {-1e30f, -1e30f, -1e30f, -1e30f};
    int   vidx[4] = {0, 0, 0, 0};

    issueChunk(0, 0);
    __syncthreads();

    for (int ch = 0; ch < NCH; ++ch) {
        int buf = ch & 1;
        if (ch + 1 < NCH) issueChunk(ch + 1, buf ^ 1);
        const _Float16* bB = (const _Float16*)(smem + buf * 16384);
        f32x4 c0 = {0, 0, 0, 0}, c1 = {0, 0, 0, 0};
#pragma unroll
        for (int kk = 0; kk < 8; ++kk) {
            int o = kk * 512 + lc * 32 + lq * 8;  // halfs
            half8 bh = *(const half8*)(bB + o);
            half8 bl = *(const half8*)(bB + 4096 + o);
            c0 = __builtin_amdgcn_mfma_f32_16x16x32_f16(afh[kk], bh, c0, 0, 0, 0);
            c1 = __builtin_amdgcn_mfma_f32_16x16x32_f16(afh[kk], bl, c1, 0, 0, 0);
            c0 = __builtin_amdgcn_mfma_f32_16x16x32_f16(afl[kk], bh, c0, 0, 0, 0);
        }
        int code = ch * 16 + lc;
#pragma unroll
        for (int r = 0; r < 4; ++r) {
            float dv = c0[r] + c1[r];
            if (dv > vmax[r]) { vmax[r] = dv; vidx[r] = code; }
        }
        __syncthreads();
    }

    // ---- argmax reduce across the 16-lane col (lc) dimension ----
#pragma unroll
    for (int m = 1; m < 16; m <<= 1) {
#pragma unroll
        for (int r = 0; r < 4; ++r) {
            float ov = __shfl_xor(vmax[r], m, 64);
            int   oi = __shfl_xor(vidx[r], m, 64);
            if (ov > vmax[r] || (ov == vmax[r] && oi < vidx[r])) {
                vmax[r] = ov; vidx[r] = oi;
            }
        }
    }
    if (lc == 0) {
#pragma unroll
        for (int r = 0; r < 4; ++r) {
            int lrow = w * 16 + lq * 4 + r;
            shLg[lrow]  = vmax[r];
            shInd[lrow] = vidx[r];
        }
    }
    __syncthreads();

    // ---- parallel gain quantization: lane j evaluates level j ----
    {
        float glv = gl[lane];
        for (int i = 0; i < 16; ++i) {
            int row = w * 16 + i;
            float gv = shLg[row];
            float lg = logf(fmaxf(gv, 1e-5f));
            float d = lg - glv; d = d * d;
            int gi = lane;
#pragma unroll
            for (int m = 1; m < 64; m <<= 1) {
                float od = __shfl_xor(d, m, 64);
                int   og = __shfl_xor(gi, m, 64);
                if (od < d || (od == d && og < gi)) { d = od; gi = og; }
            }
            if (lane == i) {
                float gsel = gl[gi];
                shGq[row] = expf(gsel);
                int sidx = shInd[row];
                ws_rowcode[row0 + row] = sidx;
                atomicAdd(ws_scnt + sidx, 1);
                atomicAdd(ws_gsum + gi, lg);
                atomicAdd(ws_gcnt + gi, 1.0f);
            }
        }
    }
    __syncthreads();

    // ---- epilogue: quantize = exp(gain_q) * cb[code] ----
    {
        float4* qv = (float4*)(out_q + (long)row0 * DIM);
#pragma unroll
        for (int it = 0; it < 16; ++it) {
            int idx = it * 256 + tid;       // 4096 float4s
            int r = idx >> 6, c4 = idx & 63;
            int code = shInd[r];
            float gq = shGq[r];
            const float4 cbv = *(const float4*)(cb + code * DIM + c4 * 4);
            float4 o;
            o.x = gq * cbv.x; o.y = gq * cbv.y; o.z = gq * cbv.z; o.w = gq * cbv.w;
            qv[idx] = o;
        }
    }
}

// K2a: exclusive prefix scan of code counts -> bucket offsets + cursors
__global__ __launch_bounds__(1024) void k_scan(const int* __restrict__ scnt,
                                               int* __restrict__ offs,
                                               int* __restrict__ curs) {
    int t = threadIdx.x;
    __shared__ int sc[1024];
    int my = scnt[t];
    sc[t] = my;
    __syncthreads();
    for (int d = 1; d < 1024; d <<= 1) {
        int v = (t >= d) ? sc[t - d] : 0;
        __syncthreads();
        sc[t] += v;
        __syncthreads();
    }
    int ex = sc[t] - my;
    offs[t] = ex;
    curs[t] = ex;
}

// K2b: scatter row ids into code-sorted buckets
__global__ __launch_bounds__(256) void k_scatter(const int* __restrict__ rowcode,
                                                 int* __restrict__ curs,
                                                 int* __restrict__ bucket) {
    int i = blockIdx.x * 256 + threadIdx.x;
    if (i < NROWS) {
        int code = rowcode[i];
        int pos = atomicAdd(curs + code, 1);
        bucket[pos] = i;
    }
}

// K2c: per-code column reduction of x + full shape/gain finalize
__global__ __launch_bounds__(256) void k_reduce(
    const float* __restrict__ x, const float* __restrict__ cb,
    const float* __restrict__ gcb, const float* __restrict__ snum,
    const float* __restrict__ gnum,
    const int* __restrict__ scnt, const int* __restrict__ offs,
    const int* __restrict__ bucket,
    const float* __restrict__ gsum, const float* __restrict__ gcnt,
    float* __restrict__ out) {
    int b = blockIdx.x, t = threadIdx.x;
    if (b < KCB) {
        int cnt = scnt[b], base = offs[b];
        float s = 0.0f;
        int i = 0;
        for (; i + 4 <= cnt; i += 4) {
            int r0 = bucket[base + i], r1 = bucket[base + i + 1];
            int r2 = bucket[base + i + 2], r3 = bucket[base + i + 3];
            float v0 = x[r0 * DIM + t], v1 = x[r1 * DIM + t];
            float v2 = x[r2 * DIM + t], v3 = x[r3 * DIM + t];
            s += v0 + v1 + v2 + v3;
        }
        for (; i < cnt; ++i) {
            int r = bucket[base + i];
            s += x[r * DIM + t];
        }
        __shared__ float red[4];
        int w = t >> 6;
        float v = s * s;
#pragma unroll
        for (int m = 32; m; m >>= 1) v += __shfl_xor(v, m, 64);
        if ((t & 63) == 0) red[w] = v;
        __syncthreads();
        float tot = red[0] + red[1] + red[2] + red[3];
        float sn = s / fmaxf(sqrtf(tot), 1e-5f);
        float u = cb[b * DIM + t] * 0.99f + 0.01f * sn;
        __syncthreads();
        v = u * u;
#pragma unroll
        for (int m = 32; m; m >>= 1) v += __shfl_xor(v, m, 64);
        if ((t & 63) == 0) red[w] = v;
        __syncthreads();
        tot = red[0] + red[1] + red[2] + red[3];
        out[OUT_SHAPE + b * DIM + t] = u / fmaxf(sqrtf(tot), 1e-12f);
        if (t == 0) out[OUT_SNUM + b] = snum[b] * 0.99f + 0.01f * (float)cnt;
    } else if (t < GK) {
        float cnt = gcnt[t];
        float gn  = gsum[t] / fmaxf(cnt, 1e-5f);
        out[OUT_GAIN + t] = gcb[t] * 0.99f + 0.01f * gn;
        out[OUT_GNUM + t] = gnum[t] * 0.99f + 0.01f * cnt;
    }
}

extern "C" void kernel_launch(void* const* d_in, const int* in_sizes, int n_in,
                              void* d_out, int out_size, void* d_ws, size_t ws_size,
                              hipStream_t stream) {
    const float* x    = (const float*)d_in[0];
    const float* cb   = (const float*)d_in[1];
    const float* gcb  = (const float*)d_in[2];
    const float* snum = (const float*)d_in[3];
    const float* gnum = (const float*)d_in[4];
    float* out = (float*)d_out;
    char*  ws  = (char*)d_ws;
    int*   ws_scnt    = (int*)(ws + WS_SCNT);
    float* ws_gsum    = (float*)(ws + WS_GSUM);
    float* ws_gcnt    = (float*)(ws + WS_GCNT);
    int*   ws_offs    = (int*)(ws + WS_OFFS);
    int*   ws_curs    = (int*)(ws + WS_CURS);
    int*   ws_rowcode = (int*)(ws + WS_ROWCODE);
    int*   ws_bucket  = (int*)(ws + WS_BUCKET);
    _Float16* cbh = (_Float16*)(ws + WS_CBHI);
    _Float16* cbl = (_Float16*)(ws + WS_CBLO);

    hipMemsetAsync(d_ws, 0, WS_ZERO_BYTES, stream);
    k_convert_cb<<<1024, 256, 0, stream>>>(cb, cbh, cbl);
    k_main<<<NROWS / TM, 256, 0, stream>>>(x, cb, gcb, cbh, cbl,
                                           ws_scnt, ws_gsum, ws_gcnt, ws_rowcode, out);
    k_scan<<<1, 1024, 0, stream>>>(ws_scnt, ws_offs, ws_curs);
    k_scatter<<<(NROWS + 255) / 256, 256, 0, stream>>>(ws_rowcode, ws_curs, ws_bucket);
    k_reduce<<<KCB + 1, 256, 0, stream>>>(x, cb, gcb, snum, gnum,
                                          ws_scnt, ws_offs, ws_bucket,
                                          ws_gsum, ws_gcnt, out);
}